// Round 11
// baseline (353.858 us; speedup 1.0000x reference)
//
#include <hip/hip_runtime.h>
#include <hip/hip_bf16.h>
#include <hip/hip_fp16.h>
#include <math.h>

#define TOKENS 32768           // 32*1024
#define EMBED  768
#define HIDDEN 3072
#define WELEMS (EMBED*HIDDEN)  // 2359296

typedef __attribute__((ext_vector_type(4))) int i32x4;          // 16 packed int8
typedef signed char i8;

__device__ __forceinline__ float wave_reduce_sum(float v) {
    for (int o = 32; o > 0; o >>= 1) v += __shfl_down(v, o);
    return v;
}
__device__ __forceinline__ float wave_reduce_max(float v) {
    for (int o = 32; o > 0; o >>= 1) v = fmaxf(v, __shfl_down(v, o));
    return v;
}

// tanh-form GELU: validated r9/r10 (absmax unchanged vs exact erf).
__device__ __forceinline__ float gelu_tanh(float x) {
    const float x2 = x * x;
    const float u  = 0.7978845608f * x * fmaf(0.044715f, x2, 1.0f);
    const float ex = __expf(u + u);                       // e^(2u)
    const float r  = __builtin_amdgcn_rcpf(ex + 1.0f);
    const float th = fmaf(-2.0f, r, 1.0f);                // tanh(u)
    const float hx = 0.5f * x;
    return fmaf(hx, th, hx);
}

// magic-number int8 round (RNE low-byte trick): validated r9/r10.
__device__ __forceinline__ unsigned int q8pack4(float v0, float v1, float v2,
                                                float v3, float qs) {
    union { float f; unsigned int i; } u0, u1, u2, u3;
    u0.f = fmaf(v0, qs, 12582912.0f);
    u1.f = fmaf(v1, qs, 12582912.0f);
    u2.f = fmaf(v2, qs, 12582912.0f);
    u3.f = fmaf(v3, qs, 12582912.0f);
    return (u0.i & 0xFFu) | ((u1.i & 0xFFu) << 8) |
           ((u2.i & 0xFFu) << 16) | ((u3.i & 0xFFu) << 24);
}

// ---- per-tensor abs-mean (two stage, deterministic) ----
__global__ __launch_bounds__(256) void k_abs_partial(const float* __restrict__ w,
                                                     float* __restrict__ out, int n) {
    float s = 0.f;
    for (int i = blockIdx.x * 256 + threadIdx.x; i < n; i += gridDim.x * 256)
        s += fabsf(w[i]);
    __shared__ float red[4];
    s = wave_reduce_sum(s);
    if ((threadIdx.x & 63) == 0) red[threadIdx.x >> 6] = s;
    __syncthreads();
    if (threadIdx.x == 0) out[blockIdx.x] = red[0] + red[1] + red[2] + red[3];
}

__global__ __launch_bounds__(256) void k_finalize(const float* __restrict__ p,
                                                  float* __restrict__ m) {
    __shared__ float r1[4], r2[4];
    float s1 = 0.f, s2 = 0.f;
    for (int i = threadIdx.x; i < 512; i += 256) { s1 += p[i]; s2 += p[512 + i]; }
    s1 = wave_reduce_sum(s1); s2 = wave_reduce_sum(s2);
    if ((threadIdx.x & 63) == 0) { r1[threadIdx.x >> 6] = s1; r2[threadIdx.x >> 6] = s2; }
    __syncthreads();
    if (threadIdx.x == 0) {
        float m1 = (r1[0] + r1[1] + r1[2] + r1[3]) / (float)WELEMS;
        float m2 = (r2[0] + r2[1] + r2[2] + r2[3]) / (float)WELEMS;
        m[0] = fmaxf(m1, 1e-5f);
        m[1] = fmaxf(m2, 1e-5f);
    }
}

// ---- ternary weight quant ----
__global__ __launch_bounds__(256) void k_quant_w(const float* __restrict__ w,
                                                 i8* __restrict__ wq,
                                                 const float* __restrict__ mp, int n) {
    const float inv = 1.0f / mp[0];
    for (int i = blockIdx.x * 256 + threadIdx.x; i < n; i += gridDim.x * 256) {
        float q = rintf(w[i] * inv);
        q = fminf(1.f, fmaxf(-1.f, q));
        wq[i] = (i8)(int)q;
    }
}

// ---- fused RMSNorm + per-token int8 absmax quant, fp32 input ----
template <int D>
__global__ __launch_bounds__(256) void k_rms_quant_f32(const float* __restrict__ x,
                                                       const float* __restrict__ g,
                                                       i8* __restrict__ xq,
                                                       float* __restrict__ sc) {
    constexpr int NV = D / 4;
    constexpr int IT = (NV + 255) / 256;
    __shared__ float reds[4], redm[4];
    const int t = blockIdx.x;
    const float4* xp = reinterpret_cast<const float4*>(x + (size_t)t * D);
    const float4* gp = reinterpret_cast<const float4*>(g);
    float4 xg[IT];
    float ssq = 0.f, amax = 0.f;
#pragma unroll
    for (int i = 0; i < IT; ++i) {
        const int idx = i * 256 + (int)threadIdx.x;
        const bool act = (NV % 256 == 0) || (idx < NV);
        if (act) {
            float4 v = xp[idx];
            float4 gv = gp[idx];
            ssq += v.x * v.x + v.y * v.y + v.z * v.z + v.w * v.w;
            xg[i].x = v.x * gv.x; xg[i].y = v.y * gv.y;
            xg[i].z = v.z * gv.z; xg[i].w = v.w * gv.w;
            amax = fmaxf(amax, fmaxf(fmaxf(fabsf(xg[i].x), fabsf(xg[i].y)),
                                     fmaxf(fabsf(xg[i].z), fabsf(xg[i].w))));
        } else {
            xg[i].x = xg[i].y = xg[i].z = xg[i].w = 0.f;
        }
    }
    ssq = wave_reduce_sum(ssq);
    amax = wave_reduce_max(amax);
    if ((threadIdx.x & 63) == 0) { reds[threadIdx.x >> 6] = ssq; redm[threadIdx.x >> 6] = amax; }
    __syncthreads();
    const float S = reds[0] + reds[1] + reds[2] + reds[3];
    const float A = fmaxf(fmaxf(redm[0], redm[1]), fmaxf(redm[2], redm[3]));
    const float rs = (float)(1.0 / sqrt((double)S / D + 1e-6));
    const float an = fmaxf(A * rs, 1e-5f);
    const float qs = rs * (127.0f / an);
    if (threadIdx.x == 0) sc[t] = an * (1.0f / 127.0f);
    unsigned int* op = reinterpret_cast<unsigned int*>(xq + (size_t)t * D);
#pragma unroll
    for (int i = 0; i < IT; ++i) {
        const int idx = i * 256 + (int)threadIdx.x;
        const bool act = (NV % 256 == 0) || (idx < NV);
        if (act)
            op[idx] = q8pack4(xg[i].x, xg[i].y, xg[i].z, xg[i].w, qs);
    }
}

// ---- fused RMSNorm + per-token int8 absmax quant, fp16 input (h) ----
template <int D>
__global__ __launch_bounds__(256) void k_rms_quant_f16(const __half* __restrict__ x,
                                                       const float* __restrict__ g,
                                                       i8* __restrict__ xq,
                                                       float* __restrict__ sc) {
    constexpr int NV = D / 8;
    constexpr int IT = (NV + 255) / 256;
    __shared__ float reds[4], redm[4];
    const int t = blockIdx.x;
    const int4* xp = reinterpret_cast<const int4*>(x + (size_t)t * D);
    const float4* gp = reinterpret_cast<const float4*>(g);
    float xg[IT][8];
    float ssq = 0.f, amax = 0.f;
#pragma unroll
    for (int i = 0; i < IT; ++i) {
        const int idx = i * 256 + (int)threadIdx.x;
        const bool act = (NV % 256 == 0) || (idx < NV);
        if (act) {
            int4 raw = xp[idx];
            const __half2* hp = reinterpret_cast<const __half2*>(&raw);
            float4 g0 = gp[idx * 2];
            float4 g1 = gp[idx * 2 + 1];
            float gv[8] = {g0.x, g0.y, g0.z, g0.w, g1.x, g1.y, g1.z, g1.w};
#pragma unroll
            for (int j = 0; j < 4; ++j) {
                float2 f = __half22float2(hp[j]);
                float a0 = f.x, a1 = f.y;
                ssq += a0 * a0 + a1 * a1;
                xg[i][j * 2]     = a0 * gv[j * 2];
                xg[i][j * 2 + 1] = a1 * gv[j * 2 + 1];
                amax = fmaxf(amax, fmaxf(fabsf(xg[i][j * 2]), fabsf(xg[i][j * 2 + 1])));
            }
        } else {
#pragma unroll
            for (int j = 0; j < 8; ++j) xg[i][j] = 0.f;
        }
    }
    ssq = wave_reduce_sum(ssq);
    amax = wave_reduce_max(amax);
    if ((threadIdx.x & 63) == 0) { reds[threadIdx.x >> 6] = ssq; redm[threadIdx.x >> 6] = amax; }
    __syncthreads();
    const float S = reds[0] + reds[1] + reds[2] + reds[3];
    const float A = fmaxf(fmaxf(redm[0], redm[1]), fmaxf(redm[2], redm[3]));
    const float rs = (float)(1.0 / sqrt((double)S / D + 1e-6));
    const float an = fmaxf(A * rs, 1e-5f);
    const float qs = rs * (127.0f / an);
    if (threadIdx.x == 0) sc[t] = an * (1.0f / 127.0f);
    unsigned int* op = reinterpret_cast<unsigned int*>(xq + (size_t)t * D);
#pragma unroll
    for (int i = 0; i < IT; ++i) {
        const int idx = i * 256 + (int)threadIdx.x;
        const bool act = (NV % 256 == 0) || (idx < NV);
        if (act) {
            op[idx * 2]     = q8pack4(xg[i][0], xg[i][1], xg[i][2], xg[i][3], qs);
            op[idx * 2 + 1] = q8pack4(xg[i][4], xg[i][5], xg[i][6], xg[i][7], qs);
        }
    }
}

// ---- 128xBN int8 MFMA GEMM, BK=64, ZERO-EXTRA-LDS double buffer ----
// Same LDS total as r10 single-buffer (GEMM1 48KB / GEMM2 32KB) -> same
// occupancy; only delta vs r10 is STAGE-first + counted vmcnt (no per-tile
// vmcnt(0) drain). Loads/thread/tile = 1 + BN/128 (A + B issues).
// LDS layout (BK=64): row pairs packed into 128-B lines; logical chunk
// lch = (row&1)*4 + c XOR'd with line&7. Each 16-lane b128 group touches
// every 16-B chunk exactly 2x -> 2-way = conflict-free (m136).
// Staging inverse (per-thread global src): t -> line=t>>3, sc=t&7,
// lch=sc^(line&7), row=2*line+(lch>>2), c=lch&3.  (rule 21 both-sides)
template <int BN, bool GELU, typename OutT>
__global__ __launch_bounds__(512, 4)
void k_gemm_i8(const i8* __restrict__ A, const i8* __restrict__ B,
               OutT* __restrict__ C, const float* __restrict__ rsc,
               const float* __restrict__ msc, int nbx, int N, int K) {
    constexpr int NI = BN / 64;          // n-fragments per wave (4 or 2)
    constexpr int NLOADS = 1 + BN / 128; // per-thread loads per tile
    __shared__ i8 As[2][64 * 128];       // 128 rows -> 64 lines, 8KB per buf
    __shared__ i8 Bs[2][(BN / 2) * 128]; // BN rows -> BN/2 lines

    // bijective XCD swizzle (m204)
    const int nwg = (int)gridDim.x;
    const int id  = (int)blockIdx.x;
    const int q = nwg >> 3, r = nwg & 7;
    const int xcd = id & 7, sub = id >> 3;
    const int swz = (xcd < r ? xcd * (q + 1) : r * (q + 1) + (xcd - r) * q) + sub;
    const int bx = swz % nbx;
    const int by = swz / nbx;

    const int tid  = (int)threadIdx.x;
    const int lane = tid & 63;
    const int wave = tid >> 6;
    const int wr = wave >> 2, wc = wave & 3;          // 2x4 wave grid
    const size_t rowBase = (size_t)by * 128;
    const size_t colBase = (size_t)bx * BN;
    const float ms = msc[0];

    i32x4 acc[4][NI] = {};

    // ---- staging source (inverse of packed-pair swizzle) ----
    const int tl   = tid >> 3;                 // line within 128-row segment
    const int lch  = (tid & 7) ^ (tl & 7);     // logical chunk
    const int rloc = tl * 2 + (lch >> 2);      // row within segment (0..127)
    const int coff = (lch & 3) * 16;           // byte offset within 64B k-row
    const i8* gA = A + (rowBase + rloc) * (size_t)K + coff;
    const i8* gB = B + (colBase + rloc) * (size_t)K + coff;

    // ---- fragment read addresses (precomputed, loop-invariant) ----
    const int frow = lane & 15;
    const int fc   = lane >> 4;                // k-chunk 0..3
    int aaddr[4], baddr[NI];
#pragma unroll
    for (int mi = 0; mi < 4; ++mi) {
        const int row = wr * 64 + mi * 16 + frow;
        const int line = row >> 1;
        const int sc = (((row & 1) << 2) + fc) ^ (line & 7);
        aaddr[mi] = line * 128 + sc * 16;
    }
#pragma unroll
    for (int ni = 0; ni < NI; ++ni) {
        const int row = wc * (BN / 4) + ni * 16 + frow;
        const int line = row >> 1;
        const int sc = (((row & 1) << 2) + fc) ^ (line & 7);
        baddr[ni] = line * 128 + sc * 16;
    }

    const int nt = K >> 6;                     // BK=64 tiles

#define STG(kk, buf)                                                           \
    {                                                                          \
        const int _k0 = (kk) << 6;                                             \
        __builtin_amdgcn_global_load_lds(                                      \
            (const __attribute__((address_space(1))) void*)(gA + _k0),         \
            (__attribute__((address_space(3))) void*)(&As[buf][tid * 16]),     \
            16, 0, 0);                                                         \
        _Pragma("unroll")                                                      \
        for (int _j = 0; _j < BN / 128; ++_j)                                  \
            __builtin_amdgcn_global_load_lds(                                  \
                (const __attribute__((address_space(1))) void*)                \
                    (gB + (size_t)_j * 128 * K + _k0),                         \
                (__attribute__((address_space(3))) void*)                      \
                    (&Bs[buf][_j * 8192 + tid * 16]),                          \
                16, 0, 0);                                                     \
    }

    STG(0, 0);                                 // prologue

    for (int t = 0; t < nt; ++t) {
        const int cur = t & 1;
        if (t + 1 < nt) {
            STG(t + 1, cur ^ 1);               // next tile in flight
            if constexpr (NLOADS == 3)         // wait ONLY tile t's loads
                asm volatile("s_waitcnt vmcnt(3)" ::: "memory");
            else
                asm volatile("s_waitcnt vmcnt(2)" ::: "memory");
        } else {
            asm volatile("s_waitcnt vmcnt(0)" ::: "memory");
        }
        __builtin_amdgcn_s_barrier();          // tile-t data visible to all
        __builtin_amdgcn_sched_barrier(0);
        i32x4 af[4], bv[NI];
#pragma unroll
        for (int mi = 0; mi < 4; ++mi)
            af[mi] = *(const i32x4*)(&As[cur][aaddr[mi]]);
#pragma unroll
        for (int ni = 0; ni < NI; ++ni)
            bv[ni] = *(const i32x4*)(&Bs[cur][baddr[ni]]);
        __builtin_amdgcn_s_setprio(1);
#pragma unroll
        for (int mi = 0; mi < 4; ++mi)
#pragma unroll
            for (int ni = 0; ni < NI; ++ni)
                acc[mi][ni] = __builtin_amdgcn_mfma_i32_16x16x64_i8(
                    af[mi], bv[ni], acc[mi][ni], 0, 0, 0);
        __builtin_amdgcn_s_setprio(0);
        __builtin_amdgcn_sched_barrier(0);
        __builtin_amdgcn_s_barrier();          // buf[cur] free for re-stage
        __builtin_amdgcn_sched_barrier(0);
    }
#undef STG

    // C/D layout: col = lane&15, row = (lane>>4)*4 + reg
    const int ccol = lane & 15;
    const int crg  = lane >> 4;
#pragma unroll
    for (int mi = 0; mi < 4; ++mi) {
#pragma unroll
        for (int i = 0; i < 4; ++i) {
            size_t row = rowBase + wr * 64 + mi * 16 + crg * 4 + i;
            float rscale = rsc[row] * ms;
#pragma unroll
            for (int ni = 0; ni < NI; ++ni) {
                size_t col = colBase + wc * (BN / 4) + ni * 16 + ccol;
                float v = (float)acc[mi][ni][i] * rscale;
                if (GELU) v = gelu_tanh(v);
                C[row * (size_t)N + col] = (OutT)v;
            }
        }
    }
}

extern "C" void kernel_launch(void* const* d_in, const int* in_sizes, int n_in,
                              void* d_out, int out_size, void* d_ws, size_t ws_size,
                              hipStream_t stream) {
    const float* x  = (const float*)d_in[0];
    const float* w1 = (const float*)d_in[1];
    const float* g1 = (const float*)d_in[2];
    const float* w2 = (const float*)d_in[3];
    const float* g2 = (const float*)d_in[4];
    float* out = (float*)d_out;

    // ---- fixed workspace region ----
    char* ws = (char*)d_ws;
    float* partials = (float*)ws;                        //       0: 4096 B
    float* mvals    = (float*)(ws + 4096);               //    4096: 256 B
    float* a        = (float*)(ws + 4352);               //    4352: 131072 B
    float* b        = (float*)(ws + 135424);             //  135424: 131072 B
    i8*    wq1      = (i8*)(ws + 266496);                //  266496: 2359296 B
    i8*    wq2      = (i8*)(ws + 2625792);               // 2625792: 2359296 B
    const size_t FIXED = 4985088;
    char* chunkMem = ws + FIXED;

    // ---- chunking: adaptive to ws_size (ws >= ~332MB -> single chunk) ----
    const size_t PER_TOK = 768 + 6144 + 3072;            // xq + h(fp16) + hq
    size_t avail = (ws_size > FIXED) ? (ws_size - FIXED) : 0;
    long long ch = (long long)(avail / PER_TOK);
    ch &= ~255LL;
    if (ch < 256) ch = 256;
    if (ch > TOKENS) ch = TOKENS;
    const int CH = (int)ch;

    // ---- weight prep ----
    k_abs_partial<<<512, 256, 0, stream>>>(w1, partials, WELEMS);
    k_abs_partial<<<512, 256, 0, stream>>>(w2, partials + 512, WELEMS);
    k_finalize<<<1, 256, 0, stream>>>(partials, mvals);
    k_quant_w<<<2048, 256, 0, stream>>>(w1, wq1, mvals + 0, WELEMS);
    k_quant_w<<<2048, 256, 0, stream>>>(w2, wq2, mvals + 1, WELEMS);

    // ---- token chunks: rms1 -> gemm1(+gelu, fp16 h) -> rms2 -> gemm2 ----
    for (int base = 0; base < TOKENS; base += CH) {
        const int rows = (TOKENS - base < CH) ? (TOKENS - base) : CH;   // mult of 256
        i8*     xqc = (i8*)chunkMem;
        __half* hc  = (__half*)(chunkMem + (size_t)CH * 768);
        i8*     hqc = (i8*)(chunkMem + (size_t)CH * 768 + (size_t)CH * 6144);

        const int nby  = rows / 128;
        const int nbx1 = HIDDEN / 256;    // 12 (BN=256)
        const int nbx2 = EMBED / 128;     // 6  (BN=128)

        k_rms_quant_f32<EMBED><<<rows, 256, 0, stream>>>(
            x + (size_t)base * EMBED, g1, xqc, a + base);
        k_gemm_i8<256, true, __half><<<nbx1 * nby, 512, 0, stream>>>(
            xqc, wq1, hc, a + base, mvals + 0, nbx1, HIDDEN, EMBED);
        k_rms_quant_f16<HIDDEN><<<rows, 256, 0, stream>>>(
            hc, g2, hqc, b + base);
        k_gemm_i8<128, false, float><<<nbx2 * nby, 512, 0, stream>>>(
            hqc, wq2, out + (size_t)base * EMBED, b + base, mvals + 1, nbx2, EMBED, HIDDEN);
    }
}

// Round 12
// 336.934 us; speedup vs baseline: 1.0502x; 1.0502x over previous
//
#include <hip/hip_runtime.h>
#include <hip/hip_bf16.h>
#include <hip/hip_fp16.h>
#include <math.h>

#define TOKENS 32768           // 32*1024
#define EMBED  768
#define HIDDEN 3072
#define WELEMS (EMBED*HIDDEN)  // 2359296

typedef __attribute__((ext_vector_type(4))) int i32x4;          // 16 packed int8
typedef signed char i8;

__device__ __forceinline__ float wave_reduce_sum(float v) {
    for (int o = 32; o > 0; o >>= 1) v += __shfl_down(v, o);
    return v;
}
__device__ __forceinline__ float wave_reduce_max(float v) {
    for (int o = 32; o > 0; o >>= 1) v = fmaxf(v, __shfl_down(v, o));
    return v;
}

// tanh-form GELU: validated r9/r10 (absmax unchanged vs exact erf).
__device__ __forceinline__ float gelu_tanh(float x) {
    const float x2 = x * x;
    const float u  = 0.7978845608f * x * fmaf(0.044715f, x2, 1.0f);
    const float ex = __expf(u + u);                       // e^(2u)
    const float r  = __builtin_amdgcn_rcpf(ex + 1.0f);
    const float th = fmaf(-2.0f, r, 1.0f);                // tanh(u)
    const float hx = 0.5f * x;
    return fmaf(hx, th, hx);
}

// magic-number int8 round (RNE low-byte trick): validated r9/r10.
__device__ __forceinline__ unsigned int q8pack4(float v0, float v1, float v2,
                                                float v3, float qs) {
    union { float f; unsigned int i; } u0, u1, u2, u3;
    u0.f = fmaf(v0, qs, 12582912.0f);
    u1.f = fmaf(v1, qs, 12582912.0f);
    u2.f = fmaf(v2, qs, 12582912.0f);
    u3.f = fmaf(v3, qs, 12582912.0f);
    return (u0.i & 0xFFu) | ((u1.i & 0xFFu) << 8) |
           ((u2.i & 0xFFu) << 16) | ((u3.i & 0xFFu) << 24);
}

// ---- fused per-tensor abs-mean partials for BOTH weights (one launch) ----
__global__ __launch_bounds__(256) void k_abs2(const float* __restrict__ w1,
                                              const float* __restrict__ w2,
                                              float* __restrict__ out) {
    const bool first = blockIdx.x < 512;
    const float* w = first ? w1 : w2;
    const int b = first ? blockIdx.x : blockIdx.x - 512;
    float s = 0.f;
    for (int i = b * 256 + threadIdx.x; i < WELEMS; i += 512 * 256)
        s += fabsf(w[i]);
    __shared__ float red[4];
    s = wave_reduce_sum(s);
    if ((threadIdx.x & 63) == 0) red[threadIdx.x >> 6] = s;
    __syncthreads();
    if (threadIdx.x == 0) out[blockIdx.x] = red[0] + red[1] + red[2] + red[3];
}

__global__ __launch_bounds__(256) void k_finalize(const float* __restrict__ p,
                                                  float* __restrict__ m) {
    __shared__ float r1[4], r2[4];
    float s1 = 0.f, s2 = 0.f;
    for (int i = threadIdx.x; i < 512; i += 256) { s1 += p[i]; s2 += p[512 + i]; }
    s1 = wave_reduce_sum(s1); s2 = wave_reduce_sum(s2);
    if ((threadIdx.x & 63) == 0) { r1[threadIdx.x >> 6] = s1; r2[threadIdx.x >> 6] = s2; }
    __syncthreads();
    if (threadIdx.x == 0) {
        float m1 = (r1[0] + r1[1] + r1[2] + r1[3]) / (float)WELEMS;
        float m2 = (r2[0] + r2[1] + r2[2] + r2[3]) / (float)WELEMS;
        m[0] = fmaxf(m1, 1e-5f);
        m[1] = fmaxf(m2, 1e-5f);
    }
}

// ---- ternary weight quant for BOTH weights (one launch) ----
__global__ __launch_bounds__(256) void k_quant_w2(const float* __restrict__ w1,
                                                  const float* __restrict__ w2,
                                                  i8* __restrict__ wq1,
                                                  i8* __restrict__ wq2,
                                                  const float* __restrict__ mp) {
    const bool first = blockIdx.x < 2048;
    const float* w = first ? w1 : w2;
    i8* wq = first ? wq1 : wq2;
    const float inv = 1.0f / (first ? mp[0] : mp[1]);
    const int b = first ? blockIdx.x : blockIdx.x - 2048;
    for (int i = b * 256 + threadIdx.x; i < WELEMS; i += 2048 * 256) {
        float q = rintf(w[i] * inv);
        q = fminf(1.f, fmaxf(-1.f, q));
        wq[i] = (i8)(int)q;
    }
}

// ---- fused RMSNorm + per-token int8 absmax quant, fp32 input ----
template <int D>
__global__ __launch_bounds__(256) void k_rms_quant_f32(const float* __restrict__ x,
                                                       const float* __restrict__ g,
                                                       i8* __restrict__ xq,
                                                       float* __restrict__ sc) {
    constexpr int NV = D / 4;
    constexpr int IT = (NV + 255) / 256;
    __shared__ float reds[4], redm[4];
    const int t = blockIdx.x;
    const float4* xp = reinterpret_cast<const float4*>(x + (size_t)t * D);
    const float4* gp = reinterpret_cast<const float4*>(g);
    float4 xg[IT];
    float ssq = 0.f, amax = 0.f;
#pragma unroll
    for (int i = 0; i < IT; ++i) {
        const int idx = i * 256 + (int)threadIdx.x;
        const bool act = (NV % 256 == 0) || (idx < NV);
        if (act) {
            float4 v = xp[idx];
            float4 gv = gp[idx];
            ssq += v.x * v.x + v.y * v.y + v.z * v.z + v.w * v.w;
            xg[i].x = v.x * gv.x; xg[i].y = v.y * gv.y;
            xg[i].z = v.z * gv.z; xg[i].w = v.w * gv.w;
            amax = fmaxf(amax, fmaxf(fmaxf(fabsf(xg[i].x), fabsf(xg[i].y)),
                                     fmaxf(fabsf(xg[i].z), fabsf(xg[i].w))));
        } else {
            xg[i].x = xg[i].y = xg[i].z = xg[i].w = 0.f;
        }
    }
    ssq = wave_reduce_sum(ssq);
    amax = wave_reduce_max(amax);
    if ((threadIdx.x & 63) == 0) { reds[threadIdx.x >> 6] = ssq; redm[threadIdx.x >> 6] = amax; }
    __syncthreads();
    const float S = reds[0] + reds[1] + reds[2] + reds[3];
    const float A = fmaxf(fmaxf(redm[0], redm[1]), fmaxf(redm[2], redm[3]));
    const float rs = (float)(1.0 / sqrt((double)S / D + 1e-6));
    const float an = fmaxf(A * rs, 1e-5f);
    const float qs = rs * (127.0f / an);
    if (threadIdx.x == 0) sc[t] = an * (1.0f / 127.0f);
    unsigned int* op = reinterpret_cast<unsigned int*>(xq + (size_t)t * D);
#pragma unroll
    for (int i = 0; i < IT; ++i) {
        const int idx = i * 256 + (int)threadIdx.x;
        const bool act = (NV % 256 == 0) || (idx < NV);
        if (act)
            op[idx] = q8pack4(xg[i].x, xg[i].y, xg[i].z, xg[i].w, qs);
    }
}

// ---- fused GELU + RMSNorm + int8 absmax quant, fp16 input (h', pre-GELU) ----
// GELU moved here from GEMM1's epilogue: this kernel is memory-bound
// (301 MB at HBM floor) with idle VALU, so the 13-op GELU is free here,
// while it was competing for issue slots against MFMA in GEMM1.
template <int D>
__global__ __launch_bounds__(256) void k_gelu_rms_quant_f16(const __half* __restrict__ x,
                                                            const float* __restrict__ g,
                                                            i8* __restrict__ xq,
                                                            float* __restrict__ sc) {
    constexpr int NV = D / 8;
    constexpr int IT = (NV + 255) / 256;
    __shared__ float reds[4], redm[4];
    const int t = blockIdx.x;
    const int4* xp = reinterpret_cast<const int4*>(x + (size_t)t * D);
    const float4* gp = reinterpret_cast<const float4*>(g);
    float xg[IT][8];
    float ssq = 0.f, amax = 0.f;
#pragma unroll
    for (int i = 0; i < IT; ++i) {
        const int idx = i * 256 + (int)threadIdx.x;
        const bool act = (NV % 256 == 0) || (idx < NV);
        if (act) {
            int4 raw = xp[idx];
            const __half2* hp = reinterpret_cast<const __half2*>(&raw);
            float4 g0 = gp[idx * 2];
            float4 g1 = gp[idx * 2 + 1];
            float gv[8] = {g0.x, g0.y, g0.z, g0.w, g1.x, g1.y, g1.z, g1.w};
#pragma unroll
            for (int j = 0; j < 4; ++j) {
                float2 f = __half22float2(hp[j]);
                float a0 = gelu_tanh(f.x);           // h = gelu(h')
                float a1 = gelu_tanh(f.y);
                ssq += a0 * a0 + a1 * a1;            // rms over h
                xg[i][j * 2]     = a0 * gv[j * 2];
                xg[i][j * 2 + 1] = a1 * gv[j * 2 + 1];
                amax = fmaxf(amax, fmaxf(fabsf(xg[i][j * 2]), fabsf(xg[i][j * 2 + 1])));
            }
        } else {
#pragma unroll
            for (int j = 0; j < 8; ++j) xg[i][j] = 0.f;
        }
    }
    ssq = wave_reduce_sum(ssq);
    amax = wave_reduce_max(amax);
    if ((threadIdx.x & 63) == 0) { reds[threadIdx.x >> 6] = ssq; redm[threadIdx.x >> 6] = amax; }
    __syncthreads();
    const float S = reds[0] + reds[1] + reds[2] + reds[3];
    const float A = fmaxf(fmaxf(redm[0], redm[1]), fmaxf(redm[2], redm[3]));
    const float rs = (float)(1.0 / sqrt((double)S / D + 1e-6));
    const float an = fmaxf(A * rs, 1e-5f);
    const float qs = rs * (127.0f / an);
    if (threadIdx.x == 0) sc[t] = an * (1.0f / 127.0f);
    unsigned int* op = reinterpret_cast<unsigned int*>(xq + (size_t)t * D);
#pragma unroll
    for (int i = 0; i < IT; ++i) {
        const int idx = i * 256 + (int)threadIdx.x;
        const bool act = (NV % 256 == 0) || (idx < NV);
        if (act) {
            op[idx * 2]     = q8pack4(xg[i][0], xg[i][1], xg[i][2], xg[i][3], qs);
            op[idx * 2 + 1] = q8pack4(xg[i][4], xg[i][5], xg[i][6], xg[i][7], qs);
        }
    }
}

// ---- 128xBN tile int8 MFMA GEMM, BK=128, single-buffer LDS (r10-proven) ----
// 512 threads = 8 waves (2M x 4N); per-wave 64 x BN/4 output.
// __launch_bounds__(512,4): 128 arch-regs/thread, zero spill (r9 lesson).
// Lean epilogue: cvt + scale + store only (GELU moved to k_gelu_rms_quant).
// Bank conflicts = 0 (rule-21 both-sides XOR swizzle); bijective XCD swizzle.
template <int BN, typename OutT>
__global__ __launch_bounds__(512, 4)
void k_gemm_i8(const i8* __restrict__ A, const i8* __restrict__ B,
               OutT* __restrict__ C, const float* __restrict__ rsc,
               const float* __restrict__ msc, int nbx, int N, int K) {
    constexpr int NI = BN / 64;          // n-fragments per wave (4 or 2)
    __shared__ i8 As[128 * 128];
    __shared__ i8 Bs[BN * 128];

    // bijective XCD swizzle (m204)
    const int nwg = (int)gridDim.x;
    const int id  = (int)blockIdx.x;
    const int q = nwg >> 3, r = nwg & 7;
    const int xcd = id & 7, sub = id >> 3;
    const int swz = (xcd < r ? xcd * (q + 1) : r * (q + 1) + (xcd - r) * q) + sub;
    const int bx = swz % nbx;
    const int by = swz / nbx;

    const int tid  = (int)threadIdx.x;
    const int lane = tid & 63;
    const int wave = tid >> 6;
    const int wr = wave >> 2, wc = wave & 3;          // 2x4 wave grid
    const size_t rowBase = (size_t)by * 128;
    const size_t colBase = (size_t)bx * BN;
    const float ms = msc[0];

    i32x4 acc[4][NI] = {};

    // staging: thread t -> row srow=t>>3 (0..63), chunk cc=t&7 (linear LDS dest);
    // global source chunk = cc ^ (srow&7)  [inverse swizzle, rule 21]
    const int srow = tid >> 3;
    const int cc   = tid & 7;
    const int gcol = (cc ^ (srow & 7)) * 16;
    const i8* gA0 = A + (rowBase + srow) * (size_t)K + gcol;
    const i8* gB0 = B + (colBase + srow) * (size_t)K + gcol;
    const int lOff = srow * 128 + cc * 16;

    const int frow = lane & 15;
    const int fko  = (lane >> 4) * 16;
    const int rswz = (frow & 7) << 4;                // read-side XOR swizzle

    for (int k0 = 0; k0 < K; k0 += 128) {
#pragma unroll
        for (int r2 = 0; r2 < 2; ++r2)
            __builtin_amdgcn_global_load_lds(
                (const __attribute__((address_space(1))) void*)(gA0 + (size_t)r2 * 64 * K + k0),
                (__attribute__((address_space(3))) void*)(&As[lOff + r2 * 64 * 128]), 16, 0, 0);
#pragma unroll
        for (int r4 = 0; r4 < BN / 64; ++r4)
            __builtin_amdgcn_global_load_lds(
                (const __attribute__((address_space(1))) void*)(gB0 + (size_t)r4 * 64 * K + k0),
                (__attribute__((address_space(3))) void*)(&Bs[lOff + r4 * 64 * 128]), 16, 0, 0);
        __syncthreads();
#pragma unroll
        for (int ks = 0; ks < 2; ++ks) {
            i32x4 af[4], bv[NI];
#pragma unroll
            for (int mi = 0; mi < 4; ++mi)
                af[mi] = *(const i32x4*)(&As[(wr * 64 + mi * 16 + frow) * 128
                                             + ((ks * 64 + fko) ^ rswz)]);
#pragma unroll
            for (int ni = 0; ni < NI; ++ni)
                bv[ni] = *(const i32x4*)(&Bs[(wc * (BN / 4) + ni * 16 + frow) * 128
                                             + ((ks * 64 + fko) ^ rswz)]);
#pragma unroll
            for (int mi = 0; mi < 4; ++mi)
#pragma unroll
                for (int ni = 0; ni < NI; ++ni)
                    acc[mi][ni] = __builtin_amdgcn_mfma_i32_16x16x64_i8(
                        af[mi], bv[ni], acc[mi][ni], 0, 0, 0);
        }
        __syncthreads();
    }

    // C/D layout: col = lane&15, row = (lane>>4)*4 + reg
    const int ccol = lane & 15;
    const int crg  = lane >> 4;
#pragma unroll
    for (int mi = 0; mi < 4; ++mi) {
#pragma unroll
        for (int i = 0; i < 4; ++i) {
            size_t row = rowBase + wr * 64 + mi * 16 + crg * 4 + i;
            float rscale = rsc[row] * ms;
#pragma unroll
            for (int ni = 0; ni < NI; ++ni) {
                size_t col = colBase + wc * (BN / 4) + ni * 16 + ccol;
                C[row * (size_t)N + col] = (OutT)((float)acc[mi][ni][i] * rscale);
            }
        }
    }
}

extern "C" void kernel_launch(void* const* d_in, const int* in_sizes, int n_in,
                              void* d_out, int out_size, void* d_ws, size_t ws_size,
                              hipStream_t stream) {
    const float* x  = (const float*)d_in[0];
    const float* w1 = (const float*)d_in[1];
    const float* g1 = (const float*)d_in[2];
    const float* w2 = (const float*)d_in[3];
    const float* g2 = (const float*)d_in[4];
    float* out = (float*)d_out;

    // ---- fixed workspace region ----
    char* ws = (char*)d_ws;
    float* partials = (float*)ws;                        //       0: 4096 B
    float* mvals    = (float*)(ws + 4096);               //    4096: 256 B
    float* a        = (float*)(ws + 4352);               //    4352: 131072 B
    float* b        = (float*)(ws + 135424);             //  135424: 131072 B
    i8*    wq1      = (i8*)(ws + 266496);                //  266496: 2359296 B
    i8*    wq2      = (i8*)(ws + 2625792);               // 2625792: 2359296 B
    const size_t FIXED = 4985088;
    char* chunkMem = ws + FIXED;

    // ---- chunking: adaptive to ws_size (ws >= ~332MB -> single chunk) ----
    const size_t PER_TOK = 768 + 6144 + 3072;            // xq + h'(fp16) + hq
    size_t avail = (ws_size > FIXED) ? (ws_size - FIXED) : 0;
    long long ch = (long long)(avail / PER_TOK);
    ch &= ~255LL;
    if (ch < 256) ch = 256;
    if (ch > TOKENS) ch = TOKENS;
    const int CH = (int)ch;

    // ---- weight prep (3 launches, was 5) ----
    k_abs2<<<1024, 256, 0, stream>>>(w1, w2, partials);
    k_finalize<<<1, 256, 0, stream>>>(partials, mvals);
    k_quant_w2<<<4096, 256, 0, stream>>>(w1, w2, wq1, wq2, mvals);

    // ---- token chunks: rms1 -> gemm1 (h' pre-GELU) -> gelu+rms2 -> gemm2 ----
    for (int base = 0; base < TOKENS; base += CH) {
        const int rows = (TOKENS - base < CH) ? (TOKENS - base) : CH;   // mult of 256
        i8*     xqc = (i8*)chunkMem;
        __half* hc  = (__half*)(chunkMem + (size_t)CH * 768);
        i8*     hqc = (i8*)(chunkMem + (size_t)CH * 768 + (size_t)CH * 6144);

        const int nby  = rows / 128;
        const int nbx1 = HIDDEN / 256;    // 12 (BN=256)
        const int nbx2 = EMBED / 128;     // 6  (BN=128)

        k_rms_quant_f32<EMBED><<<rows, 256, 0, stream>>>(
            x + (size_t)base * EMBED, g1, xqc, a + base);
        k_gemm_i8<256, __half><<<nbx1 * nby, 512, 0, stream>>>(
            xqc, wq1, hc, a + base, mvals + 0, nbx1, HIDDEN, EMBED);
        k_gelu_rms_quant_f16<HIDDEN><<<rows, 256, 0, stream>>>(
            hc, g2, hqc, b + base);
        k_gemm_i8<128, float><<<nbx2 * nby, 512, 0, stream>>>(
            hqc, wq2, out + (size_t)base * EMBED, b + base, mvals + 1, nbx2, EMBED, HIDDEN);
    }
}